// Round 1
// 66.800 us; speedup vs baseline: 1.0110x; 1.0110x over previous
//
#include <hip/hip_runtime.h>

// TtLlamaRotary: out_q[n,s,:] = xq[n,s,:] @ R[s,:,:]   (n = 0..7)
//                out_k[s,:]   = xk[s,:]   @ R[s,:,:]
// S = 128, HD = 128, fp32. Memory-bound: rot (8 MiB) read exactly once.
//
// R5 changes vs R4 (67.5 us):
//  - Dropped the xs LDS staging + first barrier. x values are loaded
//    directly from global: for fixed (i,n) the 8 d4-lanes broadcast-read
//    one address; a wave touches one 128 B coalesced segment (L1/L2-hot,
//    xq is only 0.5 MiB). This lets ALL loads issue before any wait:
//    4x R float4 (HBM, ~900 cy) first, then 36 x scalars -> single
//    latency round instead of stage->barrier->load serialization.
//  - Accumulate in ext_vector float4 -> v_pk_fma_f32 (packed fp32),
//    halving FMA issue count (144 -> 72 per lane).
//  - Grid/decode audited (R2/R3 OOB lesson): 512 blocks = (s, quarter),
//    s = bid>>2 in [0,128), R4 index max (127*32+31)=4095 float4 per s.

#define SEQ 128
#define HD  128
#define NQ  8
#define NH  9                    // 8 q heads + 1 k head fused
#define QOUT (NQ * SEQ * HD)

typedef float v4f __attribute__((ext_vector_type(4)));

__global__ __launch_bounds__(256) void rotary_kernel(
    const float* __restrict__ xq,   // [8,128,128]
    const float* __restrict__ xk,   // [128,128]
    const float* __restrict__ rot,  // [128,128,128]  R[s][h][d]
    float* __restrict__ out)        // q (131072) ++ k (16384)
{
    const int bid  = blockIdx.x;    // 512 blocks = (s, quarter)
    const int s    = bid >> 2;      // 0..127
    const int qtr  = bid & 3;       // 0..3 -> 32 d columns each
    const int tid  = threadIdx.x;   // 256 threads = 4 waves
    const int d4   = tid & 7;       // float4 slot within this 32-d quarter
    const int hg   = tid >> 3;      // 0..31: block-level h group (w*8 + lane>>3)
    const int w    = tid >> 6;      // wave id 0..3
    const int lane = tid & 63;

    __shared__ v4f red[4][8][NH];   // per-wave partials, 2.3 KiB (only LDS use)

    const v4f* __restrict__ R4 = (const v4f*)(rot + (size_t)s * HD * HD);
    const int doff = qtr * 8 + d4;  // float4 index in a 32-float4 h-row, 0..31

    // --- Issue the HBM-class loads FIRST: h = i*32 + hg, max idx 4095. ---
    v4f r[4];
#pragma unroll
    for (int i = 0; i < 4; ++i)
        r[i] = R4[(i * 32 + hg) * 32 + doff];

    // --- x values direct from global (broadcast across the 8 d4 lanes). ---
    // Per (i,n): one 128 B coalesced segment per wave; xq/xk are L2-hot.
    float xv[4][NH];
#pragma unroll
    for (int i = 0; i < 4; ++i) {
        const int h = i * 32 + hg;                       // 0..127
#pragma unroll
        for (int n = 0; n < NQ; ++n)
            xv[i][n] = xq[((size_t)n * SEQ + s) * HD + h];
        xv[i][NQ] = xk[(size_t)s * HD + h];
    }

    // --- Packed-fp32 FMA: 9 heads x 4 i x (2x v_pk_fma_f32). ---
    v4f acc[NH];
#pragma unroll
    for (int n = 0; n < NH; ++n) {
        acc[n] = r[0] * xv[0][n];
#pragma unroll
        for (int i = 1; i < 4; ++i)
            acc[n] += r[i] * xv[i][n];
    }

    // --- In-wave butterfly over the 8 resident hg groups (lane bits 3..5). ---
#pragma unroll
    for (int mask = 8; mask <= 32; mask <<= 1)
#pragma unroll
        for (int n = 0; n < NH; ++n)
#pragma unroll
            for (int c = 0; c < 4; ++c)
                acc[n][c] += __shfl_xor(acc[n][c], mask, 64);

    // Park each wave's reduced partial (lanes 0..7 hold full wave sums).
    if (lane < 8) {
#pragma unroll
        for (int n = 0; n < NH; ++n) red[w][lane][n] = acc[n];
    }
    __syncthreads();

    // 72 threads finish one (head, d4) each: sum 4 wave partials, store.
    if (tid < NH * 8) {
        const int n  = tid >> 3;   // 0..8
        const int dd = tid & 7;    // 0..7
        v4f a = red[0][dd][n];
#pragma unroll
        for (int ww = 1; ww < 4; ++ww) a += red[ww][dd][n];
        const int dbase = qtr * 32 + dd * 4;             // 0..124
        float* dst = (n < NQ)
            ? (out + ((size_t)n * SEQ + s) * HD + dbase)
            : (out + QOUT + (size_t)s * HD + dbase);
        *(v4f*)dst = a;
    }
}

extern "C" void kernel_launch(void* const* d_in, const int* in_sizes, int n_in,
                              void* d_out, int out_size, void* d_ws, size_t ws_size,
                              hipStream_t stream) {
    const float* xq  = (const float*)d_in[0];  // [1,8,128,128]
    const float* xk  = (const float*)d_in[1];  // [1,1,128,128]
    const float* rot = (const float*)d_in[2];  // [1,128,128,128]
    float* out = (float*)d_out;
    rotary_kernel<<<dim3(SEQ * 4), dim3(256), 0, stream>>>(xq, xk, rot, out);
}